// Round 1
// 249.464 us; speedup vs baseline: 1.0785x; 1.0785x over previous
//
#include <hip/hip_runtime.h>
#include <math.h>

#define IN_CH 128
#define HID   64
#define NC    10
#define BSH   8       // 256 nodes per bucket
#define NBLK  256     // partition blocks

typedef unsigned short bfu;
typedef __attribute__((ext_vector_type(8))) short bf16x8;
typedef __attribute__((ext_vector_type(4))) float f32x4;
typedef __attribute__((ext_vector_type(2))) float f32x2;

static __device__ __forceinline__ bfu bf16_of(float f) {
    unsigned u = __float_as_uint(f);
    unsigned r = (u + 0x7FFF + ((u >> 16) & 1)) >> 16;   // RNE
    return (bfu)r;
}
static __device__ __forceinline__ float f_of_bf16(bfu u) {
    return __uint_as_float(((unsigned)u) << 16);
}

// ---- fp8 e4m3 pack/unpack: HW cvt on gfx950 (imm word-select via template),
// software fallback otherwise ---------------------------------------------
#if __has_builtin(__builtin_amdgcn_cvt_pk_f32_fp8) && __has_builtin(__builtin_amdgcn_cvt_pk_fp8_f32)
template <bool HI>
static __device__ __forceinline__ f32x2 fp8_unpk(unsigned d) {
    return __builtin_amdgcn_cvt_pk_f32_fp8((int)d, HI);
}
template <bool HI>
static __device__ __forceinline__ int fp8_pk(float a, float b, int old) {
    return __builtin_amdgcn_cvt_pk_fp8_f32(a, b, old, HI);
}
#else
static __device__ __forceinline__ float fp8_dec1(unsigned b) {
    unsigned s = b >> 7, e = (b >> 3) & 15, m = b & 7;
    float v = (e == 0) ? ldexpf((float)m, -9) : ldexpf((float)(8 + m), (int)e - 10);
    return s ? -v : v;
}
static __device__ __forceinline__ unsigned fp8_enc1(float f) {
    unsigned u = __float_as_uint(f);
    unsigned s = (u >> 31) << 7;
    f = fabsf(f);
    if (!(f < 448.f)) return s | 0x7E;
    if (f < 0.015625f) {                   // subnormal range (< 2^-6)
        int q = (int)rintf(f * 512.f);
        return s | (unsigned)q;
    }
    int e; float fr = frexpf(f, &e);
    int q = (int)rintf(fr * 16.f);
    if (q == 16) { q = 8; e++; }
    int E = e + 6;
    if (E >= 16) return s | 0x7E;
    return s | (unsigned)((E << 3) | (q - 8));
}
template <bool HI>
static __device__ __forceinline__ f32x2 fp8_unpk(unsigned d) {
    unsigned w = HI ? (d >> 16) : d;
    f32x2 r; r.x = fp8_dec1(w & 0xFF); r.y = fp8_dec1((w >> 8) & 0xFF);
    return r;
}
template <bool HI>
static __device__ __forceinline__ int fp8_pk(float a, float b, int old) {
    unsigned p = fp8_enc1(a) | (fp8_enc1(b) << 8);
    return HI ? (int)(((unsigned)old & 0x0000FFFFu) | (p << 16))
              : (int)(((unsigned)old & 0xFFFF0000u) | p);
}
#endif

__device__ __forceinline__ int lower_bound_i(const int* a, int n, int v) {
    int lo = 0, hi = n;
    while (lo < hi) { int mid = (lo + hi) >> 1; if (a[mid] < v) lo = mid + 1; else hi = mid; }
    return lo;
}

// ---- init: zero bucket counters, Psum, fp8 dummy rows -------------------

__global__ void k_init(int* __restrict__ cnt, float* __restrict__ Psum,
                       unsigned* __restrict__ dumA, unsigned* __restrict__ dumB,
                       int nbuck, int ng) {
    int t = threadIdx.x;
    for (int i = t; i < nbuck; i += 512) cnt[i] = 0;
    for (int i = t; i < ng * HID; i += 512) Psum[i] = 0.f;
    if (t < 16) { dumA[t] = 0u; dumB[t] = 0u; }
}

// ---- fused partition: LDS hist -> global base claim -> scatter ----------
// Buckets get fixed-stride regions of size cap (>= 12 sigma above the mean
// bucket load), so no global scan is needed; placeC re-sorts within the
// bucket anyway, so intra-bucket order is irrelevant.

__global__ __launch_bounds__(1024) void k_part(const int* __restrict__ src,
                                               const int* __restrict__ dst,
                                               int* __restrict__ cnt,
                                               unsigned* __restrict__ packed,
                                               int E, int nbuck, int chunk, int cap) {
    __shared__ int hist[512];
    int tid = threadIdx.x;
    for (int b = tid; b < nbuck; b += 1024) hist[b] = 0;
    __syncthreads();
    int base = blockIdx.x * chunk;
    int lim  = min(base + chunk, E);
    for (int e = base + tid; e < lim; e += 1024)
        atomicAdd(&hist[dst[e] >> BSH], 1);
    __syncthreads();
    for (int b = tid; b < nbuck; b += 1024) {
        int c = hist[b];
        hist[b] = c ? atomicAdd(&cnt[b], c) : 0;   // claim contiguous sub-range
    }
    __syncthreads();
    for (int e = base + tid; e < lim; e += 1024) {   // chunk re-read hits L2
        int d = dst[e], s = src[e];
        int b = d >> BSH;
        int pos = atomicAdd(&hist[b], 1);
        if (pos < cap)   // statically impossible for this input; guards corruption
            packed[(size_t)b * (size_t)cap + pos] = ((unsigned)s << 8) | (unsigned)(d & 255);
    }
}

// ---- placeC: per bucket — histogram -> PADDED rp2 + dinv + meta ---------

__global__ __launch_bounds__(512) void k_placeC(const unsigned* __restrict__ packed,
                                                const int* __restrict__ cnt,
                                                int2* __restrict__ rp2,
                                                float* __restrict__ dinv,
                                                int* __restrict__ meta,
                                                int nn, int cap, int capm) {
    __shared__ int hist[256];
    __shared__ int scn[256];
    __shared__ int cur[256];
    int tid = threadIdx.x;
    int b   = blockIdx.x;
    int nb0 = b << BSH;
    int nnb = min(1 << BSH, nn - nb0);
    if (tid < 256) hist[tid] = 0;
    __syncthreads();
    int lo = b * cap;
    int hi = lo + min(cnt[b], cap);
    for (int e = lo + tid; e < hi; e += blockDim.x)
        atomicAdd(&hist[packed[e] & 255u], 1);
    __syncthreads();
    int pd = 0;
    if (tid < 256) { pd = (hist[tid] + 3) & ~3; scn[tid] = pd; }
    __syncthreads();
    for (int off = 1; off < 256; off <<= 1) {
        int t = 0;
        if (tid < 256 && tid >= off) t = scn[tid - off];
        __syncthreads();
        if (tid < 256) scn[tid] += t;
        __syncthreads();
    }
    int meta0 = b * capm;   // fixed-stride, 4-aligned bucket meta start
    if (tid < nnb) {
        int rp = meta0 + scn[tid] - pd;
        rp2[nb0 + tid] = make_int2(rp, rp + pd);
        cur[tid] = rp;
        dinv[nb0 + tid] = rsqrtf((float)(hist[tid] + 1));  // +1 self loop
        for (int k = hist[tid]; k < pd; k++) meta[rp + k] = nn;  // pads -> dummy row
    }
    __syncthreads();
    for (int e = lo + tid; e < hi; e += blockDim.x) {
        unsigned p = packed[e];
        int pos = atomicAdd(&cur[p & 255u], 1);
        meta[pos] = (int)(p >> 8);
    }
}

// ---- Dense X@W via MFMA bf16 + dinv-scaled fp8 epilogue -----------------

template <int K, bool IN_BF16>
__global__ __launch_bounds__(256) void k_gemm(const void* __restrict__ Xv,
                                              const float* __restrict__ W,
                                              const float* __restrict__ dinv,
                                              unsigned char* __restrict__ G8, int n) {
    constexpr int KS = K + 8;
    __shared__ bfu wt[64 * KS];
    int tid = threadIdx.x;
    for (int i = tid; i < K * 64; i += 256) {     // stage W^T as bf16 (RNE)
        int k = i >> 6, nn2 = i & 63;
        wt[nn2 * KS + k] = bf16_of(W[i]);
    }
    __syncthreads();
    int wave = tid >> 6, lane = tid & 63;
    int m = lane & 15, q = lane >> 4;
    int row0 = blockIdx.x * 64 + wave * 16;
    int rowA = min(row0 + m, n - 1);              // clamp: OOB rows never stored
    f32x4 acc[4] = {{0.f,0.f,0.f,0.f},{0.f,0.f,0.f,0.f},
                    {0.f,0.f,0.f,0.f},{0.f,0.f,0.f,0.f}};
#pragma unroll
    for (int ks = 0; ks < K / 32; ks++) {
        bf16x8 a;
        if (IN_BF16) {
            a = *(const bf16x8*)((const bfu*)Xv + (size_t)rowA * 64 + ks * 32 + q * 8);
        } else {
            const float* xp = (const float*)Xv + (size_t)rowA * K + ks * 32 + q * 8;
            float4 v0 = *(const float4*)xp;
            float4 v1 = *(const float4*)(xp + 4);
            union { unsigned u[4]; bf16x8 v; } cvt;
            cvt.u[0] = __builtin_amdgcn_perm(__float_as_uint(v0.y), __float_as_uint(v0.x), 0x07060302u);
            cvt.u[1] = __builtin_amdgcn_perm(__float_as_uint(v0.w), __float_as_uint(v0.z), 0x07060302u);
            cvt.u[2] = __builtin_amdgcn_perm(__float_as_uint(v1.y), __float_as_uint(v1.x), 0x07060302u);
            cvt.u[3] = __builtin_amdgcn_perm(__float_as_uint(v1.w), __float_as_uint(v1.z), 0x07060302u);
            a = cvt.v;
        }
#pragma unroll
        for (int nt = 0; nt < 4; nt++) {
            bf16x8 b = *(const bf16x8*)&wt[(nt * 16 + m) * KS + ks * 32 + q * 8];
            acc[nt] = __builtin_amdgcn_mfma_f32_16x16x32_bf16(a, b, acc[nt], 0, 0, 0);
        }
    }
#pragma unroll
    for (int r = 0; r < 4; r++) {
        int grow = row0 + q * 4 + r;
        if (grow < n) {
            float dv = dinv[grow];
            int p01 = fp8_pk<false>(acc[0][r] * dv, acc[1][r] * dv, 0);
            int p23 = fp8_pk<false>(acc[2][r] * dv, acc[3][r] * dv, 0);
            unsigned char* gp = G8 + (size_t)grow * 64 + m;
            gp[0]  = (unsigned char)(p01 & 0xFF);
            gp[16] = (unsigned char)((p01 >> 8) & 0xFF);
            gp[32] = (unsigned char)(p23 & 0xFF);
            gp[48] = (unsigned char)((p23 >> 8) & 0xFF);
        }
    }
}

// ---- CSR gather agg: EQUAD-PER-NODE (4 nodes/wave, 16 lanes x 4 cols) ---
// MODE 0: bf16 [N,64] out.  MODE 1: fp8 out.  MODE 2: fused mean-pool —
// per-block LDS stage of 16 nodes' rows, reduce per (graph,col) without
// atomics (batch is sorted so a block spans ~1 graph), then <=~64 nonzero
// global atomicAdds into Psum per block.

template <int MODE>
__global__ void k_agg(const unsigned* __restrict__ G4, const int* __restrict__ meta,
                      const int2* __restrict__ rp2, const float* __restrict__ dinv,
                      const float* __restrict__ bias, void* __restrict__ outv,
                      const int* __restrict__ batch, float* __restrict__ Psum,
                      int n, int ng, int do_relu, int post_scale) {
    __shared__ float pw[16][64];
    __shared__ int sb[16];
    int tid = threadIdx.x;
    int wbase = ((blockIdx.x * blockDim.x + tid) >> 6) * 4;
    if (MODE != 2) { if (wbase >= n) return; }
    int lane = tid & 63;
    int col4 = lane & 15, equad = lane >> 4;
    int nb0 = blockIdx.x * 16;                       // first node of this block
    if (MODE == 2 && tid < 16)
        sb[tid] = (nb0 + tid < n) ? batch[nb0 + tid] : -1;
    int nd    = wbase + equad;
    bool alive = nd < n;
    int ndc   = alive ? nd : (n - 1);
    int2 rp = rp2[ndc];
    int beg = rp.x, pend = alive ? rp.y : rp.x;
    f32x2 aA = {0.f, 0.f}, aB = {0.f, 0.f};
    for (int e = beg; e < pend; e += 4) {
        int4 m = *(const int4*)&meta[e];
        unsigned d0 = G4[(size_t)m.x * 16 + col4];
        unsigned d1 = G4[(size_t)m.y * 16 + col4];
        unsigned d2 = G4[(size_t)m.z * 16 + col4];
        unsigned d3 = G4[(size_t)m.w * 16 + col4];
        aA += fp8_unpk<false>(d0); aB += fp8_unpk<true>(d0);
        aA += fp8_unpk<false>(d1); aB += fp8_unpk<true>(d1);
        aA += fp8_unpk<false>(d2); aB += fp8_unpk<true>(d2);
        aA += fp8_unpk<false>(d3); aB += fp8_unpk<true>(d3);
    }
    unsigned sv = G4[(size_t)ndc * 16 + col4];   // self loop (pre-scaled)
    aA += fp8_unpk<false>(sv); aB += fp8_unpk<true>(sv);
    float dv = dinv[ndc];
    float a0 = aA.x * dv, a1 = aA.y * dv, a2 = aB.x * dv, a3 = aB.y * dv;
    if (bias) {
        float4 bv = *(const float4*)&bias[col4 * 4];
        a0 += bv.x; a1 += bv.y; a2 += bv.z; a3 += bv.w;
    }
    if (do_relu) {
        a0 = fmaxf(a0, 0.f); a1 = fmaxf(a1, 0.f);
        a2 = fmaxf(a2, 0.f); a3 = fmaxf(a3, 0.f);
    }
    if (post_scale) { a0 *= dv; a1 *= dv; a2 *= dv; a3 *= dv; }
    if (MODE == 2) {
        int slot = (tid >> 6) * 4 + equad;           // == nd - nb0
        f32x4 st;
        st.x = alive ? a0 : 0.f; st.y = alive ? a1 : 0.f;
        st.z = alive ? a2 : 0.f; st.w = alive ? a3 : 0.f;
        *(f32x4*)&pw[slot][col4 * 4] = st;           // conflict-free b128 store
        __syncthreads();
        int r = tid >> 6, c = tid & 63;
        int g0 = sb[0];
        float v = 0.f;
#pragma unroll
        for (int s2 = 0; s2 < 16; s2++)
            if (sb[s2] == g0 + r) v += pw[s2][c];
        if (v != 0.f && g0 + r < ng) atomicAdd(&Psum[(g0 + r) * 64 + c], v);
        if (tid < 16) {                              // >4-graph span fallback (never
            int bb = sb[tid];                        //   fires for ~1562-node graphs)
            if (bb > g0 + 3) {
                for (int c2 = 0; c2 < 64; c2++)
                    atomicAdd(&Psum[bb * 64 + c2], pw[tid][c2]);
            }
        }
    } else if (alive) {
        if (MODE == 1) {
            int p = fp8_pk<false>(a0, a1, 0);
            p = fp8_pk<true>(a2, a3, p);
            ((unsigned*)outv)[(size_t)nd * 16 + col4] = (unsigned)p;
        } else {
            uint2 o;
            o.x = (unsigned)bf16_of(a0) | ((unsigned)bf16_of(a1) << 16);
            o.y = (unsigned)bf16_of(a2) | ((unsigned)bf16_of(a3) << 16);
            ((uint2*)outv)[(size_t)nd * 16 + col4] = o;
        }
    }
}

// ---- mean + pooled@W3 + b3 + log_softmax --------------------------------

__global__ void k_final(const float* __restrict__ Psum, const int* __restrict__ batch,
                        int n, const float* __restrict__ W3, const float* __restrict__ b3,
                        float* __restrict__ out, int ng) {
    __shared__ float P[64 * 64];
    __shared__ float s[64][NC];
    __shared__ float lse[64];
    __shared__ float invc[64];
    int t = threadIdx.x;
    if (t < ng) {
        int lo = lower_bound_i(batch, n, t);
        int hi = lower_bound_i(batch, n, t + 1);
        invc[t] = 1.f / (float)max(hi - lo, 1);
    }
    __syncthreads();
    for (int i = t; i < ng * 64; i += blockDim.x) P[i] = Psum[i] * invc[i >> 6];
    __syncthreads();
    if (t < ng * NC) {
        int g = t / NC, c = t % NC;
        float acc = b3[c];
        for (int k = 0; k < 64; k++) acc += P[g * 64 + k] * W3[k * NC + c];
        s[g][c] = acc;
    }
    __syncthreads();
    if (t < ng) {
        float m = -1e30f;
        for (int c = 0; c < NC; c++) m = fmaxf(m, s[t][c]);
        float sum = 0.f;
        for (int c = 0; c < NC; c++) sum += expf(s[t][c] - m);
        lse[t] = m + logf(sum);
    }
    __syncthreads();
    if (t < ng * NC) {
        int g = t / NC, c = t % NC;
        out[t] = s[g][c] - lse[g];
    }
}

// ---- launch -------------------------------------------------------------

extern "C" void kernel_launch(void* const* d_in, const int* in_sizes, int n_in,
                              void* d_out, int out_size, void* d_ws, size_t ws_size,
                              hipStream_t stream) {
    const float* x     = (const float*)d_in[0];
    const int*   ei    = (const int*)  d_in[1];
    const int*   batch = (const int*)  d_in[2];
    const float* W1    = (const float*)d_in[3];
    const float* b1    = (const float*)d_in[4];
    const float* W2    = (const float*)d_in[5];
    const float* b2    = (const float*)d_in[6];
    const float* W3    = (const float*)d_in[7];
    const float* b3    = (const float*)d_in[8];
    float*       out   = (float*)d_out;

    const int NN = in_sizes[0] / IN_CH;   // 100000
    const int E  = in_sizes[1] / 2;       // 1600000
    const int NG = out_size / NC;         // 64
    const int nbuck = (NN + (1 << BSH) - 1) >> BSH;            // 391
    const int cap   = (int)(((((long long)E << BSH) / NN) + 768 + 3) & ~3LL); // 4864
    const int capm  = cap + 772;                               // + per-bucket pad slack

    const int* src = ei;
    const int* dst = ei + E;

    char* ws = (char*)d_ws;
    size_t off = 0;
    auto carve = [&](size_t bytes) -> char* {
        char* p = ws + off;
        off = (off + bytes + 255) & ~(size_t)255;
        return p;
    };
    int2*  rp2    = (int2*) carve((size_t)NN * 8);
    float* dinv   = (float*)carve((size_t)NN * 4);
    int*   cnt    = (int*)  carve((size_t)nbuck * 4);
    int*   meta   = (int*)  carve(((size_t)nbuck * capm + 64) * 4);
    unsigned char* f8A = (unsigned char*)carve((size_t)(NN + 1) * 64);  // G1 then G3
    unsigned char* f8B = (unsigned char*)carve((size_t)(NN + 1) * 64);  // G2
    bfu*   hbuf   = (bfu*)  carve((size_t)NN * HID * 2);  // H1
    float* Psum   = (float*)carve((size_t)NG * HID * 4);
    (void)ws_size;

    unsigned* packed = (unsigned*)hbuf;   // nbuck*cap*4 = 7.6 MB <= 12.8 MB (dead until agg1)

    const int chnk = (E + NBLK - 1) / NBLK;     // 6250
    const int nbG  = (NN + 63) / 64;            // 1563 (64 rows per block)
    const int nbA  = (NN + 15) / 16;            // 6250 (16 nodes per block)

    k_init<<<1, 512, 0, stream>>>(cnt, Psum,
                                  (unsigned*)(f8A + (size_t)NN * 64),
                                  (unsigned*)(f8B + (size_t)NN * 64), nbuck, NG);
    k_part<<<NBLK, 1024, 0, stream>>>(src, dst, cnt, packed, E, nbuck, chnk, cap);
    k_placeC<<<nbuck, 512, 0, stream>>>(packed, cnt, rp2, dinv, meta, NN, cap, capm);

    // layer 1: G1 = fp8(dinv*(x@W1)) ; H1 = bf16(relu(dinv*(G1[v]+sum)+b1))
    k_gemm<IN_CH, false><<<nbG, 256, 0, stream>>>(x, W1, dinv, f8A, NN);
    k_agg<0><<<nbA, 256, 0, stream>>>((const unsigned*)f8A, meta, rp2, dinv, b1,
                                      hbuf, nullptr, nullptr, NN, NG, 1, 0);
    // layer 2: G2 = fp8(dinv*(H1@W2)) ; G3 = fp8(dinv*relu(dinv*(...)+b2))
    k_gemm<HID, true><<<nbG, 256, 0, stream>>>(hbuf, W2, dinv, f8B, NN);
    k_agg<1><<<nbA, 256, 0, stream>>>((const unsigned*)f8B, meta, rp2, dinv, b2,
                                      f8A, nullptr, nullptr, NN, NG, 1, 1);
    // layer 3 fused with mean pool: Psum[g,c] += dinv*(G3[v]+sum G3[src])
    k_agg<2><<<nbA, 256, 0, stream>>>((const unsigned*)f8A, meta, rp2, dinv, nullptr,
                                      nullptr, batch, Psum, NN, NG, 0, 0);
    k_final<<<1, 640, 0, stream>>>(Psum, batch, NN, W3, b3, out, NG);
}

// Round 2
// 246.385 us; speedup vs baseline: 1.0920x; 1.0125x over previous
//
#include <hip/hip_runtime.h>
#include <math.h>

#define IN_CH 128
#define HID   64
#define NC    10
#define BSH   8       // 256 nodes per bucket
#define NBLK  256     // partition blocks

typedef unsigned short bfu;
typedef __attribute__((ext_vector_type(8))) short bf16x8;
typedef __attribute__((ext_vector_type(4))) float f32x4;
typedef __attribute__((ext_vector_type(2))) float f32x2;

static __device__ __forceinline__ bfu bf16_of(float f) {
    unsigned u = __float_as_uint(f);
    unsigned r = (u + 0x7FFF + ((u >> 16) & 1)) >> 16;   // RNE
    return (bfu)r;
}

// ---- fp8 e4m3 pack/unpack: HW cvt on gfx950 (imm word-select via template),
// software fallback otherwise ---------------------------------------------
#if __has_builtin(__builtin_amdgcn_cvt_pk_f32_fp8) && __has_builtin(__builtin_amdgcn_cvt_pk_fp8_f32)
template <bool HI>
static __device__ __forceinline__ f32x2 fp8_unpk(unsigned d) {
    return __builtin_amdgcn_cvt_pk_f32_fp8((int)d, HI);
}
template <bool HI>
static __device__ __forceinline__ int fp8_pk(float a, float b, int old) {
    return __builtin_amdgcn_cvt_pk_fp8_f32(a, b, old, HI);
}
#else
static __device__ __forceinline__ float fp8_dec1(unsigned b) {
    unsigned s = b >> 7, e = (b >> 3) & 15, m = b & 7;
    float v = (e == 0) ? ldexpf((float)m, -9) : ldexpf((float)(8 + m), (int)e - 10);
    return s ? -v : v;
}
static __device__ __forceinline__ unsigned fp8_enc1(float f) {
    unsigned u = __float_as_uint(f);
    unsigned s = (u >> 31) << 7;
    f = fabsf(f);
    if (!(f < 448.f)) return s | 0x7E;
    if (f < 0.015625f) {                   // subnormal range (< 2^-6)
        int q = (int)rintf(f * 512.f);
        return s | (unsigned)q;
    }
    int e; float fr = frexpf(f, &e);
    int q = (int)rintf(fr * 16.f);
    if (q == 16) { q = 8; e++; }
    int E = e + 6;
    if (E >= 16) return s | 0x7E;
    return s | (unsigned)((E << 3) | (q - 8));
}
template <bool HI>
static __device__ __forceinline__ f32x2 fp8_unpk(unsigned d) {
    unsigned w = HI ? (d >> 16) : d;
    f32x2 r; r.x = fp8_dec1(w & 0xFF); r.y = fp8_dec1((w >> 8) & 0xFF);
    return r;
}
template <bool HI>
static __device__ __forceinline__ int fp8_pk(float a, float b, int old) {
    unsigned p = fp8_enc1(a) | (fp8_enc1(b) << 8);
    return HI ? (int)(((unsigned)old & 0x0000FFFFu) | (p << 16))
              : (int)(((unsigned)old & 0xFFFF0000u) | p);
}
#endif

__device__ __forceinline__ int lower_bound_i(const int* a, int n, int v) {
    int lo = 0, hi = n;
    while (lo < hi) { int mid = (lo + hi) >> 1; if (a[mid] < v) lo = mid + 1; else hi = mid; }
    return lo;
}

// ---- init: zero bucket counters, Psum, fp8 dummy rows -------------------

__global__ void k_init(int* __restrict__ cnt, float* __restrict__ Psum,
                       unsigned* __restrict__ dumA, unsigned* __restrict__ dumB,
                       int nbuck, int ng) {
    int t = threadIdx.x;
    for (int i = t; i < nbuck; i += 512) cnt[i] = 0;
    for (int i = t; i < ng * HID; i += 512) Psum[i] = 0.f;
    if (t < 16) { dumA[t] = 0u; dumB[t] = 0u; }
}

// ---- fused partition: LDS hist -> global base claim -> scatter ----------
// Buckets get fixed-stride regions of size cap (>= 12 sigma above the mean
// bucket load), so no global scan is needed; placeC re-sorts within the
// bucket anyway, so intra-bucket order is irrelevant.

__global__ __launch_bounds__(1024) void k_part(const int* __restrict__ src,
                                               const int* __restrict__ dst,
                                               int* __restrict__ cnt,
                                               unsigned* __restrict__ packed,
                                               int E, int nbuck, int chunk, int cap) {
    __shared__ int hist[512];
    int tid = threadIdx.x;
    for (int b = tid; b < nbuck; b += 1024) hist[b] = 0;
    __syncthreads();
    int base = blockIdx.x * chunk;
    int lim  = min(base + chunk, E);
    for (int e = base + tid; e < lim; e += 1024)
        atomicAdd(&hist[dst[e] >> BSH], 1);
    __syncthreads();
    for (int b = tid; b < nbuck; b += 1024) {
        int c = hist[b];
        hist[b] = c ? atomicAdd(&cnt[b], c) : 0;   // claim contiguous sub-range
    }
    __syncthreads();
    for (int e = base + tid; e < lim; e += 1024) {   // chunk re-read hits L2
        int d = dst[e], s = src[e];
        int b = d >> BSH;
        int pos = atomicAdd(&hist[b], 1);
        if (pos < cap)   // statically impossible for this input; guards corruption
            packed[(size_t)b * (size_t)cap + pos] = ((unsigned)s << 8) | (unsigned)(d & 255);
    }
}

// ---- placeC: per bucket — histogram -> PADDED rp2 + dinv + meta ---------

__global__ __launch_bounds__(512) void k_placeC(const unsigned* __restrict__ packed,
                                                const int* __restrict__ cnt,
                                                int2* __restrict__ rp2,
                                                float* __restrict__ dinv,
                                                int* __restrict__ meta,
                                                int nn, int cap, int capm) {
    __shared__ int hist[256];
    __shared__ int scn[256];
    __shared__ int cur[256];
    int tid = threadIdx.x;
    int b   = blockIdx.x;
    int nb0 = b << BSH;
    int nnb = min(1 << BSH, nn - nb0);
    if (tid < 256) hist[tid] = 0;
    __syncthreads();
    int lo = b * cap;
    int hi = lo + min(cnt[b], cap);
    for (int e = lo + tid; e < hi; e += blockDim.x)
        atomicAdd(&hist[packed[e] & 255u], 1);
    __syncthreads();
    int pd = 0;
    if (tid < 256) { pd = (hist[tid] + 3) & ~3; scn[tid] = pd; }
    __syncthreads();
    for (int off = 1; off < 256; off <<= 1) {
        int t = 0;
        if (tid < 256 && tid >= off) t = scn[tid - off];
        __syncthreads();
        if (tid < 256) scn[tid] += t;
        __syncthreads();
    }
    int meta0 = b * capm;   // fixed-stride, 4-aligned bucket meta start
    if (tid < nnb) {
        int rp = meta0 + scn[tid] - pd;
        rp2[nb0 + tid] = make_int2(rp, rp + pd);
        cur[tid] = rp;
        dinv[nb0 + tid] = rsqrtf((float)(hist[tid] + 1));  // +1 self loop
        for (int k = hist[tid]; k < pd; k++) meta[rp + k] = nn;  // pads -> dummy row
    }
    __syncthreads();
    for (int e = lo + tid; e < hi; e += blockDim.x) {
        unsigned p = packed[e];
        int pos = atomicAdd(&cur[p & 255u], 1);
        meta[pos] = (int)(p >> 8);
    }
}

// ---- Dense X@W via MFMA bf16 + dinv-scaled fp8 epilogue -----------------

template <int K, bool IN_BF16>
__global__ __launch_bounds__(256) void k_gemm(const void* __restrict__ Xv,
                                              const float* __restrict__ W,
                                              const float* __restrict__ dinv,
                                              unsigned char* __restrict__ G8, int n) {
    constexpr int KS = K + 8;
    __shared__ bfu wt[64 * KS];
    int tid = threadIdx.x;
    for (int i = tid; i < K * 64; i += 256) {     // stage W^T as bf16 (RNE)
        int k = i >> 6, nn2 = i & 63;
        wt[nn2 * KS + k] = bf16_of(W[i]);
    }
    __syncthreads();
    int wave = tid >> 6, lane = tid & 63;
    int m = lane & 15, q = lane >> 4;
    int row0 = blockIdx.x * 64 + wave * 16;
    int rowA = min(row0 + m, n - 1);              // clamp: OOB rows never stored
    f32x4 acc[4] = {{0.f,0.f,0.f,0.f},{0.f,0.f,0.f,0.f},
                    {0.f,0.f,0.f,0.f},{0.f,0.f,0.f,0.f}};
#pragma unroll
    for (int ks = 0; ks < K / 32; ks++) {
        bf16x8 a;
        if (IN_BF16) {
            a = *(const bf16x8*)((const bfu*)Xv + (size_t)rowA * 64 + ks * 32 + q * 8);
        } else {
            const float* xp = (const float*)Xv + (size_t)rowA * K + ks * 32 + q * 8;
            float4 v0 = *(const float4*)xp;
            float4 v1 = *(const float4*)(xp + 4);
            union { unsigned u[4]; bf16x8 v; } cvt;
            cvt.u[0] = __builtin_amdgcn_perm(__float_as_uint(v0.y), __float_as_uint(v0.x), 0x07060302u);
            cvt.u[1] = __builtin_amdgcn_perm(__float_as_uint(v0.w), __float_as_uint(v0.z), 0x07060302u);
            cvt.u[2] = __builtin_amdgcn_perm(__float_as_uint(v1.y), __float_as_uint(v1.x), 0x07060302u);
            cvt.u[3] = __builtin_amdgcn_perm(__float_as_uint(v1.w), __float_as_uint(v1.z), 0x07060302u);
            a = cvt.v;
        }
#pragma unroll
        for (int nt = 0; nt < 4; nt++) {
            bf16x8 b = *(const bf16x8*)&wt[(nt * 16 + m) * KS + ks * 32 + q * 8];
            acc[nt] = __builtin_amdgcn_mfma_f32_16x16x32_bf16(a, b, acc[nt], 0, 0, 0);
        }
    }
#pragma unroll
    for (int r = 0; r < 4; r++) {
        int grow = row0 + q * 4 + r;
        if (grow < n) {
            float dv = dinv[grow];
            int p01 = fp8_pk<false>(acc[0][r] * dv, acc[1][r] * dv, 0);
            int p23 = fp8_pk<false>(acc[2][r] * dv, acc[3][r] * dv, 0);
            unsigned char* gp = G8 + (size_t)grow * 64 + m;
            gp[0]  = (unsigned char)(p01 & 0xFF);
            gp[16] = (unsigned char)((p01 >> 8) & 0xFF);
            gp[32] = (unsigned char)(p23 & 0xFF);
            gp[48] = (unsigned char)((p23 >> 8) & 0xFF);
        }
    }
}

// ---- CSR gather agg: EQUAD-PER-NODE (4 nodes/wave, 16 lanes x 4 cols) ---
// MODE 1: fp8 out.  MODE 2: fused mean-pool (LDS block reduce -> few global
// atomics; batch sorted so a block spans ~1 graph).  MODE 3: fused @W2 —
// stage the block's 16 aggregated H1 rows + W2^T in LDS as bf16, 2 MFMAs
// per wave (16x16 col-tile, K=64), dinv-scale + fp8 store of G2. Kills the
// 25.6 MB H1 round-trip and one kernel launch.

template <int MODE>
__global__ void k_agg(const unsigned* __restrict__ G4, const int* __restrict__ meta,
                      const int2* __restrict__ rp2, const float* __restrict__ dinv,
                      const float* __restrict__ bias, void* __restrict__ outv,
                      const int* __restrict__ batch, float* __restrict__ Psum,
                      const float* __restrict__ Wg,
                      int n, int ng, int do_relu, int post_scale) {
    extern __shared__ char smem[];
    int tid = threadIdx.x;
    if (MODE == 3) {                                 // stage W2^T as bf16 [64][72]
        bfu* wt = (bfu*)(smem + 16 * 72 * 2);
        for (int i = tid; i < 64 * 64; i += 256) {
            int k = i >> 6, c = i & 63;
            wt[c * 72 + k] = bf16_of(Wg[i]);
        }
    }
    int wbase = ((blockIdx.x * blockDim.x + tid) >> 6) * 4;
    if (MODE == 1) { if (wbase >= n) return; }       // barrier modes never early-out
    int lane = tid & 63;
    int col4 = lane & 15, equad = lane >> 4;
    int nb0 = blockIdx.x * 16;                       // first node of this block
    if (MODE == 2 && tid < 16) {
        int* sb = (int*)(smem + 16 * 64 * 4);
        sb[tid] = (nb0 + tid < n) ? batch[nb0 + tid] : -1;
    }
    int nd    = wbase + equad;
    bool alive = nd < n;
    int ndc   = alive ? nd : (n - 1);
    int2 rp = rp2[ndc];
    int beg = rp.x, pend = alive ? rp.y : rp.x;
    f32x2 aA = {0.f, 0.f}, aB = {0.f, 0.f};
    for (int e = beg; e < pend; e += 4) {
        int4 m = *(const int4*)&meta[e];
        unsigned d0 = G4[(size_t)m.x * 16 + col4];
        unsigned d1 = G4[(size_t)m.y * 16 + col4];
        unsigned d2 = G4[(size_t)m.z * 16 + col4];
        unsigned d3 = G4[(size_t)m.w * 16 + col4];
        aA += fp8_unpk<false>(d0); aB += fp8_unpk<true>(d0);
        aA += fp8_unpk<false>(d1); aB += fp8_unpk<true>(d1);
        aA += fp8_unpk<false>(d2); aB += fp8_unpk<true>(d2);
        aA += fp8_unpk<false>(d3); aB += fp8_unpk<true>(d3);
    }
    unsigned sv = G4[(size_t)ndc * 16 + col4];   // self loop (pre-scaled)
    aA += fp8_unpk<false>(sv); aB += fp8_unpk<true>(sv);
    float dv = dinv[ndc];
    float a0 = aA.x * dv, a1 = aA.y * dv, a2 = aB.x * dv, a3 = aB.y * dv;
    if (bias) {
        float4 bv = *(const float4*)&bias[col4 * 4];
        a0 += bv.x; a1 += bv.y; a2 += bv.z; a3 += bv.w;
    }
    if (do_relu) {
        a0 = fmaxf(a0, 0.f); a1 = fmaxf(a1, 0.f);
        a2 = fmaxf(a2, 0.f); a3 = fmaxf(a3, 0.f);
    }
    if (post_scale) { a0 *= dv; a1 *= dv; a2 *= dv; a3 *= dv; }
    if (MODE == 3) {
        bfu* pw = (bfu*)smem;                        // [16][72] bf16 H1 rows
        bfu* wt = (bfu*)(smem + 16 * 72 * 2);
        int slot = (tid >> 6) * 4 + equad;           // == nd - nb0
        uint2 o;
        o.x = (unsigned)bf16_of(alive ? a0 : 0.f) | ((unsigned)bf16_of(alive ? a1 : 0.f) << 16);
        o.y = (unsigned)bf16_of(alive ? a2 : 0.f) | ((unsigned)bf16_of(alive ? a3 : 0.f) << 16);
        *(uint2*)&pw[slot * 72 + col4 * 4] = o;
        __syncthreads();
        int w = tid >> 6, m = col4, q = equad;
        f32x4 acc = {0.f, 0.f, 0.f, 0.f};
#pragma unroll
        for (int ks = 0; ks < 2; ks++) {
            bf16x8 av = *(const bf16x8*)&pw[m * 72 + ks * 32 + q * 8];
            bf16x8 bv = *(const bf16x8*)&wt[(w * 16 + m) * 72 + ks * 32 + q * 8];
            acc = __builtin_amdgcn_mfma_f32_16x16x32_bf16(av, bv, acc, 0, 0, 0);
        }
        int c = w * 16 + m;                          // output col; rows q*4+r
        int r0 = nb0 + q * 4;
        float dv0 = dinv[min(r0 + 0, n - 1)], dv1 = dinv[min(r0 + 1, n - 1)];
        float dv2 = dinv[min(r0 + 2, n - 1)], dv3 = dinv[min(r0 + 3, n - 1)];
        int p01 = fp8_pk<false>(acc[0] * dv0, acc[1] * dv1, 0);
        int p23 = fp8_pk<false>(acc[2] * dv2, acc[3] * dv3, 0);
        unsigned char* gp = (unsigned char*)outv;
        if (r0 + 0 < n) gp[(size_t)(r0 + 0) * 64 + c] = (unsigned char)(p01 & 0xFF);
        if (r0 + 1 < n) gp[(size_t)(r0 + 1) * 64 + c] = (unsigned char)((p01 >> 8) & 0xFF);
        if (r0 + 2 < n) gp[(size_t)(r0 + 2) * 64 + c] = (unsigned char)(p23 & 0xFF);
        if (r0 + 3 < n) gp[(size_t)(r0 + 3) * 64 + c] = (unsigned char)((p23 >> 8) & 0xFF);
    } else if (MODE == 2) {
        float* pwf = (float*)smem;                   // [16][64] fp32
        int*   sb  = (int*)(smem + 16 * 64 * 4);
        int slot = (tid >> 6) * 4 + equad;           // == nd - nb0
        f32x4 st;
        st.x = alive ? a0 : 0.f; st.y = alive ? a1 : 0.f;
        st.z = alive ? a2 : 0.f; st.w = alive ? a3 : 0.f;
        *(f32x4*)&pwf[slot * 64 + col4 * 4] = st;    // conflict-free b128 store
        __syncthreads();
        int r = tid >> 6, cc = tid & 63;
        int g0 = sb[0];
        float v = 0.f;
#pragma unroll
        for (int s2 = 0; s2 < 16; s2++)
            if (sb[s2] == g0 + r) v += pwf[s2 * 64 + cc];
        if (v != 0.f && g0 + r < ng) atomicAdd(&Psum[(g0 + r) * 64 + cc], v);
        if (tid < 16) {                              // >4-graph span fallback (never
            int bb = sb[tid];                        //   fires for ~1562-node graphs)
            if (bb > g0 + 3) {
                for (int c2 = 0; c2 < 64; c2++)
                    atomicAdd(&Psum[bb * 64 + c2], pwf[tid * 64 + c2]);
            }
        }
    } else if (alive) {                              // MODE 1: fp8 out
        int p = fp8_pk<false>(a0, a1, 0);
        p = fp8_pk<true>(a2, a3, p);
        ((unsigned*)outv)[(size_t)nd * 16 + col4] = (unsigned)p;
    }
}

// ---- mean + pooled@W3 + b3 + log_softmax --------------------------------

__global__ void k_final(const float* __restrict__ Psum, const int* __restrict__ batch,
                        int n, const float* __restrict__ W3, const float* __restrict__ b3,
                        float* __restrict__ out, int ng) {
    __shared__ float P[64 * 64];
    __shared__ float s[64][NC];
    __shared__ float lse[64];
    __shared__ float invc[64];
    int t = threadIdx.x;
    if (t < ng) {
        int lo = lower_bound_i(batch, n, t);
        int hi = lower_bound_i(batch, n, t + 1);
        invc[t] = 1.f / (float)max(hi - lo, 1);
    }
    __syncthreads();
    for (int i = t; i < ng * 64; i += blockDim.x) P[i] = Psum[i] * invc[i >> 6];
    __syncthreads();
    if (t < ng * NC) {
        int g = t / NC, c = t % NC;
        float acc = b3[c];
        for (int k = 0; k < 64; k++) acc += P[g * 64 + k] * W3[k * NC + c];
        s[g][c] = acc;
    }
    __syncthreads();
    if (t < ng) {
        float m = -1e30f;
        for (int c = 0; c < NC; c++) m = fmaxf(m, s[t][c]);
        float sum = 0.f;
        for (int c = 0; c < NC; c++) sum += expf(s[t][c] - m);
        lse[t] = m + logf(sum);
    }
    __syncthreads();
    if (t < ng * NC) {
        int g = t / NC, c = t % NC;
        out[t] = s[g][c] - lse[g];
    }
}

// ---- launch -------------------------------------------------------------

extern "C" void kernel_launch(void* const* d_in, const int* in_sizes, int n_in,
                              void* d_out, int out_size, void* d_ws, size_t ws_size,
                              hipStream_t stream) {
    const float* x     = (const float*)d_in[0];
    const int*   ei    = (const int*)  d_in[1];
    const int*   batch = (const int*)  d_in[2];
    const float* W1    = (const float*)d_in[3];
    const float* b1    = (const float*)d_in[4];
    const float* W2    = (const float*)d_in[5];
    const float* b2    = (const float*)d_in[6];
    const float* W3    = (const float*)d_in[7];
    const float* b3    = (const float*)d_in[8];
    float*       out   = (float*)d_out;

    const int NN = in_sizes[0] / IN_CH;   // 100000
    const int E  = in_sizes[1] / 2;       // 1600000
    const int NG = out_size / NC;         // 64
    const int nbuck = (NN + (1 << BSH) - 1) >> BSH;            // 391
    const int cap   = (int)(((((long long)E << BSH) / NN) + 768 + 3) & ~3LL); // 4864
    const int capm  = cap + 772;                               // + per-bucket pad slack

    const int* src = ei;
    const int* dst = ei + E;

    char* ws = (char*)d_ws;
    size_t off = 0;
    auto carve = [&](size_t bytes) -> char* {
        char* p = ws + off;
        off = (off + bytes + 255) & ~(size_t)255;
        return p;
    };
    int2*  rp2    = (int2*) carve((size_t)NN * 8);
    float* dinv   = (float*)carve((size_t)NN * 4);
    int*   cnt    = (int*)  carve((size_t)nbuck * 4);
    int*   meta   = (int*)  carve(((size_t)nbuck * capm + 64) * 4);
    unsigned char* f8A = (unsigned char*)carve((size_t)(NN + 1) * 64);  // G1 then G3
    unsigned char* f8B = (unsigned char*)carve((size_t)(NN + 1) * 64);  // G2
    unsigned* packed = (unsigned*)carve((size_t)nbuck * cap * 4);
    float* Psum   = (float*)carve((size_t)NG * HID * 4);
    (void)ws_size;

    const int chnk = (E + NBLK - 1) / NBLK;     // 6250
    const int nbG  = (NN + 63) / 64;            // 1563 (64 rows per block)
    const int nbA  = (NN + 15) / 16;            // 6250 (16 nodes per block)

    const int smem3 = (16 * 72 + 64 * 72) * 2;  // pw + wt (bf16)
    const int smem2 = 16 * 64 * 4 + 16 * 4;     // pwf + sb

    k_init<<<1, 512, 0, stream>>>(cnt, Psum,
                                  (unsigned*)(f8A + (size_t)NN * 64),
                                  (unsigned*)(f8B + (size_t)NN * 64), nbuck, NG);
    k_part<<<NBLK, 1024, 0, stream>>>(src, dst, cnt, packed, E, nbuck, chnk, cap);
    k_placeC<<<nbuck, 512, 0, stream>>>(packed, cnt, rp2, dinv, meta, NN, cap, capm);

    // layer 1: G1 = fp8(dinv*(x@W1))
    k_gemm<IN_CH, false><<<nbG, 256, 0, stream>>>(x, W1, dinv, f8A, NN);
    // layer 1 agg + layer 2 gemm fused: G2 = fp8(dinv*(relu(dinv*(G1 sum)+b1)@W2))
    k_agg<3><<<nbA, 256, smem3, stream>>>((const unsigned*)f8A, meta, rp2, dinv, b1,
                                          f8B, nullptr, nullptr, W2, NN, NG, 1, 0);
    // layer 2 agg: G3 = fp8(dinv*relu(dinv*(G2 sum)+b2))
    k_agg<1><<<nbA, 256, 0, stream>>>((const unsigned*)f8B, meta, rp2, dinv, b2,
                                      f8A, nullptr, nullptr, nullptr, NN, NG, 1, 1);
    // layer 3 fused with mean pool: Psum[g,c] += dinv*(G3[v]+sum G3[src])
    k_agg<2><<<nbA, 256, smem2, stream>>>((const unsigned*)f8A, meta, rp2, dinv, nullptr,
                                          nullptr, batch, Psum, nullptr, NN, NG, 0, 0);
    k_final<<<1, 640, 0, stream>>>(Psum, batch, NN, W3, b3, out, NG);
}

// Round 4
// 231.981 us; speedup vs baseline: 1.1598x; 1.0621x over previous
//
#include <hip/hip_runtime.h>
#include <math.h>

#define IN_CH 128
#define HID   64
#define NC    10
#define BSH   8       // 256 nodes per bucket
#define NBLK  256     // partition blocks

typedef unsigned short bfu;
typedef __attribute__((ext_vector_type(8))) short bf16x8;
typedef __attribute__((ext_vector_type(4))) float f32x4;
typedef __attribute__((ext_vector_type(2))) float f32x2;

static __device__ __forceinline__ bfu bf16_of(float f) {
    unsigned u = __float_as_uint(f);
    unsigned r = (u + 0x7FFF + ((u >> 16) & 1)) >> 16;   // RNE
    return (bfu)r;
}

// ---- fp8 e4m3 pack/unpack: HW cvt on gfx950 (imm word-select via template),
// software fallback otherwise ---------------------------------------------
#if __has_builtin(__builtin_amdgcn_cvt_pk_f32_fp8) && __has_builtin(__builtin_amdgcn_cvt_pk_fp8_f32)
template <bool HI>
static __device__ __forceinline__ f32x2 fp8_unpk(unsigned d) {
    return __builtin_amdgcn_cvt_pk_f32_fp8((int)d, HI);
}
template <bool HI>
static __device__ __forceinline__ int fp8_pk(float a, float b, int old) {
    return __builtin_amdgcn_cvt_pk_fp8_f32(a, b, old, HI);
}
#else
static __device__ __forceinline__ float fp8_dec1(unsigned b) {
    unsigned s = b >> 7, e = (b >> 3) & 15, m = b & 7;
    float v = (e == 0) ? ldexpf((float)m, -9) : ldexpf((float)(8 + m), (int)e - 10);
    return s ? -v : v;
}
static __device__ __forceinline__ unsigned fp8_enc1(float f) {
    unsigned u = __float_as_uint(f);
    unsigned s = (u >> 31) << 7;
    f = fabsf(f);
    if (!(f < 448.f)) return s | 0x7E;
    if (f < 0.015625f) {                   // subnormal range (< 2^-6)
        int q = (int)rintf(f * 512.f);
        return s | (unsigned)q;
    }
    int e; float fr = frexpf(f, &e);
    int q = (int)rintf(fr * 16.f);
    if (q == 16) { q = 8; e++; }
    int E = e + 6;
    if (E >= 16) return s | 0x7E;
    return s | (unsigned)((E << 3) | (q - 8));
}
template <bool HI>
static __device__ __forceinline__ f32x2 fp8_unpk(unsigned d) {
    unsigned w = HI ? (d >> 16) : d;
    f32x2 r; r.x = fp8_dec1(w & 0xFF); r.y = fp8_dec1((w >> 8) & 0xFF);
    return r;
}
template <bool HI>
static __device__ __forceinline__ int fp8_pk(float a, float b, int old) {
    unsigned p = fp8_enc1(a) | (fp8_enc1(b) << 8);
    return HI ? (int)(((unsigned)old & 0x0000FFFFu) | (p << 16))
              : (int)(((unsigned)old & 0xFFFF0000u) | p);
}
#endif

__device__ __forceinline__ int lower_bound_i(const int* a, int n, int v) {
    int lo = 0, hi = n;
    while (lo < hi) { int mid = (lo + hi) >> 1; if (a[mid] < v) lo = mid + 1; else hi = mid; }
    return lo;
}

// ---- init (8 blocks): zero cnt/Psum/dummies + pre-convert W1,W2 to bf16
// in the exact LDS-tile layouts ([64][136] / [64][72]) so the MFMA kernels
// stage with pure uint4 copies instead of per-block fp32->bf16 conversion.

__global__ void k_init(int* __restrict__ cnt, float* __restrict__ Psum,
                       unsigned* __restrict__ dumA, unsigned* __restrict__ dumB,
                       const float* __restrict__ W1, const float* __restrict__ W2,
                       bfu* __restrict__ W1b, bfu* __restrict__ W2b,
                       int nbuck, int ng) {
    int t = threadIdx.x, b = blockIdx.x;
    if (b == 0) {
        for (int i = t; i < nbuck; i += 256) cnt[i] = 0;
        if (t < 16) { dumA[t] = 0u; dumB[t] = 0u; }
    } else if (b == 1) {
        for (int i = t; i < ng * HID; i += 256) Psum[i] = 0.f;
    } else if (b < 6) {
        int base = (b - 2) * 2048;
        for (int i = t; i < 2048; i += 256) {
            int idx = base + i;                 // over 128*64, idx = k*64+c
            int k = idx >> 6, c = idx & 63;
            W1b[c * 136 + k] = bf16_of(W1[idx]);
        }
    } else {
        int base = (b - 6) * 2048;
        for (int i = t; i < 2048; i += 256) {
            int idx = base + i;                 // over 64*64, idx = k*64+c
            int k = idx >> 6, c = idx & 63;
            W2b[c * 72 + k] = bf16_of(W2[idx]);
        }
    }
}

// ---- fused partition: LDS hist -> global base claim -> scatter ----------
// Buckets get fixed-stride regions of size cap (>= 12 sigma above the mean
// bucket load), so no global scan is needed; placeC re-sorts within the
// bucket anyway, so intra-bucket order is irrelevant.

__global__ __launch_bounds__(1024) void k_part(const int* __restrict__ src,
                                               const int* __restrict__ dst,
                                               int* __restrict__ cnt,
                                               unsigned* __restrict__ packed,
                                               int E, int nbuck, int chunk, int cap) {
    __shared__ int hist[512];
    int tid = threadIdx.x;
    for (int b = tid; b < nbuck; b += 1024) hist[b] = 0;
    __syncthreads();
    int base = blockIdx.x * chunk;
    int lim  = min(base + chunk, E);
    for (int e = base + tid; e < lim; e += 1024)
        atomicAdd(&hist[dst[e] >> BSH], 1);
    __syncthreads();
    for (int b = tid; b < nbuck; b += 1024) {
        int c = hist[b];
        hist[b] = c ? atomicAdd(&cnt[b], c) : 0;   // claim contiguous sub-range
    }
    __syncthreads();
    for (int e = base + tid; e < lim; e += 1024) {   // chunk re-read hits L2
        int d = dst[e], s = src[e];
        int b = d >> BSH;
        int pos = atomicAdd(&hist[b], 1);
        if (pos < cap)   // statically impossible for this input; guards corruption
            packed[(size_t)b * (size_t)cap + pos] = ((unsigned)s << 8) | (unsigned)(d & 255);
    }
}

// ---- placeC: per bucket — histogram -> PADDED rp2 + dinv + meta ---------

__global__ __launch_bounds__(1024) void k_placeC(const unsigned* __restrict__ packed,
                                                 const int* __restrict__ cnt,
                                                 int2* __restrict__ rp2,
                                                 float* __restrict__ dinv,
                                                 int* __restrict__ meta,
                                                 int nn, int cap, int capm) {
    __shared__ int hist[256];
    __shared__ int scn[256];
    __shared__ int cur[256];
    int tid = threadIdx.x;
    int b   = blockIdx.x;
    int nb0 = b << BSH;
    int nnb = min(1 << BSH, nn - nb0);
    if (tid < 256) hist[tid] = 0;
    __syncthreads();
    int lo = b * cap;
    int hi = lo + min(cnt[b], cap);
    for (int e = lo + tid; e < hi; e += blockDim.x)
        atomicAdd(&hist[packed[e] & 255u], 1);
    __syncthreads();
    int pd = 0;
    if (tid < 256) { pd = (hist[tid] + 3) & ~3; scn[tid] = pd; }
    __syncthreads();
    for (int off = 1; off < 256; off <<= 1) {
        int t = 0;
        if (tid < 256 && tid >= off) t = scn[tid - off];
        __syncthreads();
        if (tid < 256) scn[tid] += t;
        __syncthreads();
    }
    int meta0 = b * capm;   // fixed-stride, 4-aligned bucket meta start
    if (tid < nnb) {
        int rp = meta0 + scn[tid] - pd;
        rp2[nb0 + tid] = make_int2(rp, rp + pd);
        cur[tid] = rp;
        dinv[nb0 + tid] = rsqrtf((float)(hist[tid] + 1));  // +1 self loop
        for (int k = hist[tid]; k < pd; k++) meta[rp + k] = nn;  // pads -> dummy row
    }
    __syncthreads();
    for (int e = lo + tid; e < hi; e += blockDim.x) {
        unsigned p = packed[e];
        int pos = atomicAdd(&cur[p & 255u], 1);
        meta[pos] = (int)(p >> 8);
    }
}

// ---- Dense X@W via MFMA bf16 + dinv-scaled fp8 epilogue -----------------
// W arrives pre-converted bf16 in LDS layout; staging is a pure uint4 copy.

template <int K, bool IN_BF16>
__global__ __launch_bounds__(256) void k_gemm(const void* __restrict__ Xv,
                                              const bfu* __restrict__ Wb,
                                              const float* __restrict__ dinv,
                                              unsigned char* __restrict__ G8, int n) {
    constexpr int KS = K + 8;
    __shared__ bfu wt[64 * KS];
    int tid = threadIdx.x;
    {
        const uint4* wsrc = (const uint4*)Wb;
        uint4* wdst = (uint4*)wt;
        for (int i = tid; i < 8 * KS; i += 256) wdst[i] = wsrc[i];
    }
    __syncthreads();
    int wave = tid >> 6, lane = tid & 63;
    int m = lane & 15, q = lane >> 4;
    int row0 = blockIdx.x * 64 + wave * 16;
    int rowA = min(row0 + m, n - 1);              // clamp: OOB rows never stored
    f32x4 acc[4] = {{0.f,0.f,0.f,0.f},{0.f,0.f,0.f,0.f},
                    {0.f,0.f,0.f,0.f},{0.f,0.f,0.f,0.f}};
#pragma unroll
    for (int ks = 0; ks < K / 32; ks++) {
        bf16x8 a;
        if (IN_BF16) {
            a = *(const bf16x8*)((const bfu*)Xv + (size_t)rowA * 64 + ks * 32 + q * 8);
        } else {
            const float* xp = (const float*)Xv + (size_t)rowA * K + ks * 32 + q * 8;
            float4 v0 = *(const float4*)xp;
            float4 v1 = *(const float4*)(xp + 4);
            union { unsigned u[4]; bf16x8 v; } cvt;
            cvt.u[0] = __builtin_amdgcn_perm(__float_as_uint(v0.y), __float_as_uint(v0.x), 0x07060302u);
            cvt.u[1] = __builtin_amdgcn_perm(__float_as_uint(v0.w), __float_as_uint(v0.z), 0x07060302u);
            cvt.u[2] = __builtin_amdgcn_perm(__float_as_uint(v1.y), __float_as_uint(v1.x), 0x07060302u);
            cvt.u[3] = __builtin_amdgcn_perm(__float_as_uint(v1.w), __float_as_uint(v1.z), 0x07060302u);
            a = cvt.v;
        }
#pragma unroll
        for (int nt = 0; nt < 4; nt++) {
            bf16x8 b = *(const bf16x8*)&wt[(nt * 16 + m) * KS + ks * 32 + q * 8];
            acc[nt] = __builtin_amdgcn_mfma_f32_16x16x32_bf16(a, b, acc[nt], 0, 0, 0);
        }
    }
#pragma unroll
    for (int r = 0; r < 4; r++) {
        int grow = row0 + q * 4 + r;
        if (grow < n) {
            float dv = dinv[grow];
            int p01 = fp8_pk<false>(acc[0][r] * dv, acc[1][r] * dv, 0);
            int p23 = fp8_pk<false>(acc[2][r] * dv, acc[3][r] * dv, 0);
            unsigned char* gp = G8 + (size_t)grow * 64 + m;
            gp[0]  = (unsigned char)(p01 & 0xFF);
            gp[16] = (unsigned char)((p01 >> 8) & 0xFF);
            gp[32] = (unsigned char)(p23 & 0xFF);
            gp[48] = (unsigned char)((p23 >> 8) & 0xFF);
        }
    }
}

// ---- CSR gather agg: EQUAD-PER-NODE (4 nodes/wave, 16 lanes x 4 cols) ---
// 8 edges in flight per iteration (2x int4 meta, 8 independent gathers)
// for MLP depth; 4-edge tail (pads are mod-4).
// MODE 1: fp8 out.  MODE 2: fused mean-pool.  MODE 3: fused @W2 via MFMA.

template <int MODE>
__global__ void k_agg(const unsigned* __restrict__ G4, const int* __restrict__ meta,
                      const int2* __restrict__ rp2, const float* __restrict__ dinv,
                      const float* __restrict__ bias, void* __restrict__ outv,
                      const int* __restrict__ batch, float* __restrict__ Psum,
                      const bfu* __restrict__ Wb,
                      int n, int ng, int do_relu, int post_scale) {
    extern __shared__ char smem[];
    int tid = threadIdx.x;
    if (MODE == 3) {                                 // stage W2^T bf16 [64][72]
        bfu* wt = (bfu*)(smem + 16 * 72 * 2);
        const uint4* wsrc = (const uint4*)Wb;
        uint4* wdst = (uint4*)wt;
        for (int i = tid; i < 576; i += 256) wdst[i] = wsrc[i];
    }
    int wbase = ((blockIdx.x * blockDim.x + tid) >> 6) * 4;
    if (MODE == 1) { if (wbase >= n) return; }       // barrier modes never early-out
    int lane = tid & 63;
    int col4 = lane & 15, equad = lane >> 4;
    int nb0 = blockIdx.x * 16;                       // first node of this block
    if (MODE == 2 && tid < 16) {
        int* sb = (int*)(smem + 16 * 64 * 4);
        sb[tid] = (nb0 + tid < n) ? batch[nb0 + tid] : -1;
    }
    int nd    = wbase + equad;
    bool alive = nd < n;
    int ndc   = alive ? nd : (n - 1);
    int2 rp = rp2[ndc];
    int beg = rp.x, pend = alive ? rp.y : rp.x;
    unsigned sv = G4[(size_t)ndc * 16 + col4];   // self loop: issue before loop
    float dv = dinv[ndc];
    f32x2 aA = {0.f, 0.f}, aB = {0.f, 0.f};
    int e = beg;
    for (; e + 8 <= pend; e += 8) {
        int4 m0 = *(const int4*)&meta[e];
        int4 m1 = *(const int4*)&meta[e + 4];
        unsigned d0 = G4[(size_t)m0.x * 16 + col4];
        unsigned d1 = G4[(size_t)m0.y * 16 + col4];
        unsigned d2 = G4[(size_t)m0.z * 16 + col4];
        unsigned d3 = G4[(size_t)m0.w * 16 + col4];
        unsigned d4 = G4[(size_t)m1.x * 16 + col4];
        unsigned d5 = G4[(size_t)m1.y * 16 + col4];
        unsigned d6 = G4[(size_t)m1.z * 16 + col4];
        unsigned d7 = G4[(size_t)m1.w * 16 + col4];
        aA += fp8_unpk<false>(d0); aB += fp8_unpk<true>(d0);
        aA += fp8_unpk<false>(d1); aB += fp8_unpk<true>(d1);
        aA += fp8_unpk<false>(d2); aB += fp8_unpk<true>(d2);
        aA += fp8_unpk<false>(d3); aB += fp8_unpk<true>(d3);
        aA += fp8_unpk<false>(d4); aB += fp8_unpk<true>(d4);
        aA += fp8_unpk<false>(d5); aB += fp8_unpk<true>(d5);
        aA += fp8_unpk<false>(d6); aB += fp8_unpk<true>(d6);
        aA += fp8_unpk<false>(d7); aB += fp8_unpk<true>(d7);
    }
    if (e < pend) {                                  // exactly 4 remain
        int4 m = *(const int4*)&meta[e];
        unsigned d0 = G4[(size_t)m.x * 16 + col4];
        unsigned d1 = G4[(size_t)m.y * 16 + col4];
        unsigned d2 = G4[(size_t)m.z * 16 + col4];
        unsigned d3 = G4[(size_t)m.w * 16 + col4];
        aA += fp8_unpk<false>(d0); aB += fp8_unpk<true>(d0);
        aA += fp8_unpk<false>(d1); aB += fp8_unpk<true>(d1);
        aA += fp8_unpk<false>(d2); aB += fp8_unpk<true>(d2);
        aA += fp8_unpk<false>(d3); aB += fp8_unpk<true>(d3);
    }
    aA += fp8_unpk<false>(sv); aB += fp8_unpk<true>(sv);
    float a0 = aA.x * dv, a1 = aA.y * dv, a2 = aB.x * dv, a3 = aB.y * dv;
    if (bias) {
        float4 bv = *(const float4*)&bias[col4 * 4];
        a0 += bv.x; a1 += bv.y; a2 += bv.z; a3 += bv.w;
    }
    if (do_relu) {
        a0 = fmaxf(a0, 0.f); a1 = fmaxf(a1, 0.f);
        a2 = fmaxf(a2, 0.f); a3 = fmaxf(a3, 0.f);
    }
    if (post_scale) { a0 *= dv; a1 *= dv; a2 *= dv; a3 *= dv; }
    if (MODE == 3) {
        bfu* pw = (bfu*)smem;                        // [16][72] bf16 H1 rows
        bfu* wt = (bfu*)(smem + 16 * 72 * 2);
        int slot = (tid >> 6) * 4 + equad;           // == nd - nb0
        uint2 o;
        o.x = (unsigned)bf16_of(alive ? a0 : 0.f) | ((unsigned)bf16_of(alive ? a1 : 0.f) << 16);
        o.y = (unsigned)bf16_of(alive ? a2 : 0.f) | ((unsigned)bf16_of(alive ? a3 : 0.f) << 16);
        *(uint2*)&pw[slot * 72 + col4 * 4] = o;
        __syncthreads();
        int w = tid >> 6, m = col4, q = equad;
        f32x4 acc = {0.f, 0.f, 0.f, 0.f};
#pragma unroll
        for (int ks = 0; ks < 2; ks++) {
            bf16x8 av = *(const bf16x8*)&pw[m * 72 + ks * 32 + q * 8];
            bf16x8 bv = *(const bf16x8*)&wt[(w * 16 + m) * 72 + ks * 32 + q * 8];
            acc = __builtin_amdgcn_mfma_f32_16x16x32_bf16(av, bv, acc, 0, 0, 0);
        }
        int c = w * 16 + m;                          // output col; rows q*4+r
        int r0 = nb0 + q * 4;
        float dv0 = dinv[min(r0 + 0, n - 1)], dv1 = dinv[min(r0 + 1, n - 1)];
        float dv2 = dinv[min(r0 + 2, n - 1)], dv3 = dinv[min(r0 + 3, n - 1)];
        int p01 = fp8_pk<false>(acc[0] * dv0, acc[1] * dv1, 0);
        int p23 = fp8_pk<false>(acc[2] * dv2, acc[3] * dv3, 0);
        unsigned char* gp = (unsigned char*)outv;
        if (r0 + 0 < n) gp[(size_t)(r0 + 0) * 64 + c] = (unsigned char)(p01 & 0xFF);
        if (r0 + 1 < n) gp[(size_t)(r0 + 1) * 64 + c] = (unsigned char)((p01 >> 8) & 0xFF);
        if (r0 + 2 < n) gp[(size_t)(r0 + 2) * 64 + c] = (unsigned char)(p23 & 0xFF);
        if (r0 + 3 < n) gp[(size_t)(r0 + 3) * 64 + c] = (unsigned char)((p23 >> 8) & 0xFF);
    } else if (MODE == 2) {
        float* pwf = (float*)smem;                   // [16][64] fp32
        int*   sb  = (int*)(smem + 16 * 64 * 4);
        int slot = (tid >> 6) * 4 + equad;           // == nd - nb0
        f32x4 st;
        st.x = alive ? a0 : 0.f; st.y = alive ? a1 : 0.f;
        st.z = alive ? a2 : 0.f; st.w = alive ? a3 : 0.f;
        *(f32x4*)&pwf[slot * 64 + col4 * 4] = st;    // conflict-free b128 store
        __syncthreads();
        int r = tid >> 6, cc = tid & 63;
        int g0 = sb[0];
        float v = 0.f;
#pragma unroll
        for (int s2 = 0; s2 < 16; s2++)
            if (sb[s2] == g0 + r) v += pwf[s2 * 64 + cc];
        if (v != 0.f && g0 + r < ng) atomicAdd(&Psum[(g0 + r) * 64 + cc], v);
        if (tid < 16) {                              // >4-graph span fallback (never
            int bb = sb[tid];                        //   fires for ~1562-node graphs)
            if (bb > g0 + 3) {
                for (int c2 = 0; c2 < 64; c2++)
                    atomicAdd(&Psum[bb * 64 + c2], pwf[tid * 64 + c2]);
            }
        }
    } else if (alive) {                              // MODE 1: fp8 out
        int p = fp8_pk<false>(a0, a1, 0);
        p = fp8_pk<true>(a2, a3, p);
        ((unsigned*)outv)[(size_t)nd * 16 + col4] = (unsigned)p;
    }
}

// ---- mean + pooled@W3 + b3 + log_softmax --------------------------------

__global__ void k_final(const float* __restrict__ Psum, const int* __restrict__ batch,
                        int n, const float* __restrict__ W3, const float* __restrict__ b3,
                        float* __restrict__ out, int ng) {
    __shared__ float P[64 * 64];
    __shared__ float s[64][NC];
    __shared__ float lse[64];
    __shared__ float invc[64];
    int t = threadIdx.x;
    if (t < ng) {
        int lo = lower_bound_i(batch, n, t);
        int hi = lower_bound_i(batch, n, t + 1);
        invc[t] = 1.f / (float)max(hi - lo, 1);
    }
    __syncthreads();
    for (int i = t; i < ng * 64; i += blockDim.x) P[i] = Psum[i] * invc[i >> 6];
    __syncthreads();
    if (t < ng * NC) {
        int g = t / NC, c = t % NC;
        float acc = b3[c];
        for (int k = 0; k < 64; k++) acc += P[g * 64 + k] * W3[k * NC + c];
        s[g][c] = acc;
    }
    __syncthreads();
    if (t < ng) {
        float m = -1e30f;
        for (int c = 0; c < NC; c++) m = fmaxf(m, s[t][c]);
        float sum = 0.f;
        for (int c = 0; c < NC; c++) sum += expf(s[t][c] - m);
        lse[t] = m + logf(sum);
    }
    __syncthreads();
    if (t < ng * NC) {
        int g = t / NC, c = t % NC;
        out[t] = s[g][c] - lse[g];
    }
}

// ---- launch -------------------------------------------------------------

extern "C" void kernel_launch(void* const* d_in, const int* in_sizes, int n_in,
                              void* d_out, int out_size, void* d_ws, size_t ws_size,
                              hipStream_t stream) {
    const float* x     = (const float*)d_in[0];
    const int*   ei    = (const int*)  d_in[1];
    const int*   batch = (const int*)  d_in[2];
    const float* W1    = (const float*)d_in[3];
    const float* b1    = (const float*)d_in[4];
    const float* W2    = (const float*)d_in[5];
    const float* b2    = (const float*)d_in[6];
    const float* W3    = (const float*)d_in[7];
    const float* b3    = (const float*)d_in[8];
    float*       out   = (float*)d_out;

    const int NN = in_sizes[0] / IN_CH;   // 100000
    const int E  = in_sizes[1] / 2;       // 1600000
    const int NG = out_size / NC;         // 64
    const int nbuck = (NN + (1 << BSH) - 1) >> BSH;            // 391
    const int cap   = (int)(((((long long)E << BSH) / NN) + 768 + 3) & ~3LL); // 4864
    const int capm  = cap + 772;                               // + per-bucket pad slack

    const int* src = ei;
    const int* dst = ei + E;

    char* ws = (char*)d_ws;
    size_t off = 0;
    auto carve = [&](size_t bytes) -> char* {
        char* p = ws + off;
        off = (off + bytes + 255) & ~(size_t)255;
        return p;
    };
    int2*  rp2    = (int2*) carve((size_t)NN * 8);
    float* dinv   = (float*)carve((size_t)NN * 4);
    int*   cnt    = (int*)  carve((size_t)nbuck * 4);
    int*   meta   = (int*)  carve(((size_t)nbuck * capm + 64) * 4);
    unsigned char* f8A = (unsigned char*)carve((size_t)(NN + 1) * 64);  // G1 then G3
    unsigned char* f8B = (unsigned char*)carve((size_t)(NN + 1) * 64);  // G2
    unsigned* packed = (unsigned*)carve((size_t)nbuck * cap * 4);
    float* Psum   = (float*)carve((size_t)NG * HID * 4);
    bfu*   W1b    = (bfu*)  carve((size_t)64 * 136 * 2);
    bfu*   W2b    = (bfu*)  carve((size_t)64 * 72 * 2);
    (void)ws_size;

    const int chnk = (E + NBLK - 1) / NBLK;     // 6250
    const int nbG  = (NN + 63) / 64;            // 1563 (64 rows per block)
    const int nbA  = (NN + 15) / 16;            // 6250 (16 nodes per block)

    const int smem3 = (16 * 72 + 64 * 72) * 2;  // pw + wt (bf16)
    const int smem2 = 16 * 64 * 4 + 16 * 4;     // pwf + sb

    k_init<<<8, 256, 0, stream>>>(cnt, Psum,
                                  (unsigned*)(f8A + (size_t)NN * 64),
                                  (unsigned*)(f8B + (size_t)NN * 64),
                                  W1, W2, W1b, W2b, nbuck, NG);
    k_part<<<NBLK, 1024, 0, stream>>>(src, dst, cnt, packed, E, nbuck, chnk, cap);
    k_placeC<<<nbuck, 1024, 0, stream>>>(packed, cnt, rp2, dinv, meta, NN, cap, capm);

    // layer 1: G1 = fp8(dinv*(x@W1))
    k_gemm<IN_CH, false><<<nbG, 256, 0, stream>>>(x, W1b, dinv, f8A, NN);
    // layer 1 agg + layer 2 gemm fused: G2 = fp8(dinv*(relu(dinv*(G1 sum)+b1)@W2))
    k_agg<3><<<nbA, 256, smem3, stream>>>((const unsigned*)f8A, meta, rp2, dinv, b1,
                                          f8B, nullptr, nullptr, W2b, NN, NG, 1, 0);
    // layer 2 agg: G3 = fp8(dinv*relu(dinv*(G2 sum)+b2))
    k_agg<1><<<nbA, 256, 0, stream>>>((const unsigned*)f8B, meta, rp2, dinv, b2,
                                      f8A, nullptr, nullptr, nullptr, NN, NG, 1, 1);
    // layer 3 fused with mean pool: Psum[g,c] += dinv*(G3[v]+sum G3[src])
    k_agg<2><<<nbA, 256, smem2, stream>>>((const unsigned*)f8A, meta, rp2, dinv, nullptr,
                                          nullptr, batch, Psum, nullptr, NN, NG, 0, 0);
    k_final<<<1, 640, 0, stream>>>(Psum, batch, NN, W3, b3, out, NG);
}